// Round 1
// 160.823 us; speedup vs baseline: 1.0509x; 1.0509x over previous
//
#include <hip/hip_runtime.h>

// Zero-phase bandpass FIR = one 8191-tap correlation with the kernel
// autocorrelation g, as an implicit-Toeplitz MFMA GEMM.
//   out[t] = sum_s g[s] * xe[t + s],  g = autocorr(k) (bf16, hi only)
// Round 6: software-pipelined main loop. A-fragments prefetched one Q-step
// ahead into ping-pong registers (kills L2 latency on the Toeplitz table);
// B ds_reads issued at step top ahead of the MFMA cluster; s_setprio(1)
// around MFMAs; XCD-aware bijective block swizzle; kz/g-zero fused into
// the xe builder (5 kernels -> 4).

#define T_LEN   131072
#define XE_LEN  139776
#define XE_U4   (XE_LEN / 8)      // 17472 uint4 per row
#define NCHUNK  312               // A chunks: table P in [0,312), p = P-24
#define QQ      72                // Q-steps per wave
#define SCH     8                 // Q-steps per LDS chunk
#define NCH     9                 // chunks per wave

typedef float  f32x4  __attribute__((ext_vector_type(4)));
typedef __bf16 bf16x8 __attribute__((ext_vector_type(8)));

// ---------- ws layout (bytes) ----------
#define WS_KZ   0                 // 12288 floats (zero-padded k)
#define WS_G    49152             // 8192 floats  (autocorrelation)
#define WS_AHI  81920             // 312*512 bf16 Toeplitz frags = 319488 B
#define WS_XE   401408            // 32*139776 bf16 padded signal
#define WS_END  9347072

__device__ __forceinline__ void gload_lds16(const uint4* g, uint4* lds) {
  __builtin_amdgcn_global_load_lds(
      (const __attribute__((address_space(1))) unsigned int*)g,
      (__attribute__((address_space(3))) unsigned int*)lds, 16, 0, 0);
}

// K1: g[s] += partial over 256-long i-chunk; grid (32, 16).
__global__ void k_autocorr(const float* __restrict__ k,
                           const float* __restrict__ kz,
                           float* __restrict__ g) {
  int s = blockIdx.x * 256 + threadIdx.x;
  int i0 = blockIdx.y * 256;
  const float* kk  = k + i0;
  const float* kzs = kz + (8191 - s) + i0;   // 4-B aligned only
  float a0 = 0.f, a1 = 0.f, a2 = 0.f, a3 = 0.f;
  #pragma unroll 4
  for (int i = 0; i < 256; i += 4) {
    float4 kv = *(const float4*)(kk + i);
    float4 zv;
    __builtin_memcpy(&zv, kzs + i, 16);
    a0 = fmaf(kv.x, zv.x, a0);
    a1 = fmaf(kv.y, zv.y, a1);
    a2 = fmaf(kv.z, zv.z, a2);
    a3 = fmaf(kv.w, zv.w, a3);
  }
  atomicAdd(&g[s], (a0 + a1) + (a2 + a3));
}

// K2: Toeplitz A fragments, fragment-ordered (chunk P, lane l, 8 bf16).
// A_p[i][k] = gpad[32p + k - i], lane l: i = l&15, k = (l>>4)*8 + jj.
__global__ void k_build_afrag(const float* __restrict__ g,
                              __bf16* __restrict__ Ahi) {
  int P = blockIdx.x;
  int t = threadIdx.x;
  int l = t >> 2;
  int jj0 = (t & 3) * 2;
  int q = l >> 4, i = l & 15;
  int p = P - 24;
  #pragma unroll
  for (int u = 0; u < 2; ++u) {
    int jj = jj0 + u;
    int s = 32 * p + 8 * q + jj - i;
    float val = (s >= 0 && s <= 8190) ? g[s] : 0.0f;
    Ahi[P * 512 + l * 8 + jj] = (__bf16)val;
  }
}

// K0 (fused): xe[row][w] = bf16( X(w-4095) ), reflect in [-2048, T+2048),
// else 0. blockIdx.y==0 additionally builds kz (zero-padded k) and zeros g.
__global__ void k_build_xe(const float* __restrict__ x, __bf16* __restrict__ xe,
                           const float* __restrict__ k, float* __restrict__ kz,
                           float* __restrict__ g) {
  if (blockIdx.y == 0) {           // fused former k_build_kz
    int m = blockIdx.x * 256 + threadIdx.x;
    if (m < 12288) {
      int i = m - 4096;
      kz[m] = (i >= 0 && i < 4096) ? k[i] : 0.0f;
    }
    if (m < 8192) g[m] = 0.0f;
  }
  int e0 = (blockIdx.x * 256 + threadIdx.x) * 8;
  int row = blockIdx.y;
  if (e0 >= XE_LEN) return;
  const float* xr = x + (size_t)row * T_LEN;
  int v0 = e0 - 4095;
  bf16x8 outv;
  if (v0 >= 0 && v0 <= T_LEN - 8) {
    float4 f0, f1;
    __builtin_memcpy(&f0, xr + v0, 16);
    __builtin_memcpy(&f1, xr + v0 + 4, 16);
    outv[0] = (__bf16)f0.x; outv[1] = (__bf16)f0.y;
    outv[2] = (__bf16)f0.z; outv[3] = (__bf16)f0.w;
    outv[4] = (__bf16)f1.x; outv[5] = (__bf16)f1.y;
    outv[6] = (__bf16)f1.z; outv[7] = (__bf16)f1.w;
  } else {
    #pragma unroll
    for (int u = 0; u < 8; ++u) {
      int v = v0 + u;
      float val = 0.0f;
      if (v >= -2048 && v < T_LEN + 2048) {
        int v2 = v < 0 ? -v : v;
        v2 = v2 >= T_LEN ? 2 * T_LEN - 2 - v2 : v2;
        val = xr[v2];
      }
      outv[u] = (__bf16)val;
    }
  }
  ((uint4*)(xe + (size_t)row * XE_LEN))[e0 >> 3] =
      __builtin_bit_cast(uint4, outv);
}

// One software-pipelined Q-step. ACUR holds this step's 4 A frags (loaded
// one step earlier); ANXT receives next step's. B read at step top (8
// pipelined ds_read_b128 cover their own ~120cy latency before first use).
// Chunk boundary (Qr==0, ch>0): vmcnt(0) drains staging issued 8 steps ago
// (~free), flip buf, then issue next chunk's async staging into buf^1 --
// whose last ds_read completed before the previous step's MFMAs (lgkmcnt),
// same hazard profile as the round-5 kernel.
#define FIR_STEP(ACUR, ANXT)                                               \
  {                                                                        \
    const int ch = Qi >> 3, Qr = Qi & 7;                                   \
    if (Qr == 0) {                                                         \
      if (ch > 0) {                                                        \
        asm volatile("s_waitcnt vmcnt(0)" ::: "memory");                   \
        buf ^= 1;                                                          \
      }                                                                    \
      if (ch < NCH - 1) {                                                  \
        uint4* dst = sw + ((buf ^ 1) << 9);                                \
        const uint4* src = gbase + ((ch + 1) << 5);                        \
        _Pragma("unroll")                                                  \
        for (int r = 0; r < 8; ++r)                                        \
          gload_lds16(src + (size_t)r * XE_U4, dst + (r << 6));            \
      }                                                                    \
    }                                                                      \
    const uint4* bp = sw + (buf << 9) + lofs + (Qr << 2);                  \
    bf16x8 Bv[8];                                                          \
    _Pragma("unroll")                                                      \
    for (int r = 0; r < 8; ++r)                                            \
      Bv[r] = __builtin_bit_cast(bf16x8, bp[r << 6]);                      \
    if (Qi < QQ - 1) {                                                     \
      const int nQ = Qbeg + Qi + 1;                                        \
      _Pragma("unroll")                                                    \
      for (int mt = 0; mt < 4; ++mt)                                       \
        ANXT[mt] =                                                         \
            __builtin_bit_cast(bf16x8, Ahi[(nQ + 24 - 8 * mt) * 64 + l]);  \
    }                                                                      \
    __builtin_amdgcn_s_setprio(1);                                         \
    _Pragma("unroll")                                                      \
    for (int r = 0; r < 8; ++r)                                            \
      _Pragma("unroll")                                                    \
      for (int mt = 0; mt < 4; ++mt)                                       \
        acc[r][mt] = __builtin_amdgcn_mfma_f32_16x16x32_bf16(              \
            ACUR[mt], Bv[r], acc[r][mt], 0, 0, 0);                         \
    __builtin_amdgcn_s_setprio(0);                                         \
    ++Qi;                                                                  \
  }

// Main: 256 threads = 4 waves; wave w computes Q-quarter w (72 Q-steps) of
// one 8-row x 1024-t tile. Grid: flat 512 blocks with XCD-aware bijective
// swizzle (each XCD's 64 blocks share a contiguous 1.2 MB xe panel in L2).
__global__ __launch_bounds__(256, 2) void k_fir_mfma(
    const uint4* __restrict__ xeu, const uint4* __restrict__ Ahi,
    float* __restrict__ out) {
  __shared__ uint4 sbB[4096];      // 64 KB: wave*1024 + buf*512 + row*64

  const int tid = threadIdx.x;
  const int w   = tid >> 6;                  // wave = Q-quarter
  const int l   = tid & 63;
  const int q   = l >> 4;
  const int n   = l & 15;

  // XCD swizzle: 512 blocks, 8 XCDs -> 64 contiguous flat ids per XCD.
  // flat order = by*128 + bx, so one XCD covers (by fixed, 64 bx-tiles).
  const int orig = blockIdx.x;
  const int flat = (orig & 7) * 64 + (orig >> 3);
  const int bx   = flat & 127;
  const int by   = flat >> 7;

  const int t0    = bx << 10;                // 1024 outputs per block
  const int rbase = by << 3;                 // 8 rows per block
  const int Qbeg  = w * QQ;
  const int lofs  = q + 2 * n;               // uint4 offset in B window

  // per-lane global base for staging (lane l covers uint4 slot l of a row)
  const uint4* gbase = xeu + (size_t)rbase * XE_U4 + (t0 >> 3) + 4 * Qbeg + l;
  uint4* sw = sbB + (w << 10);

  f32x4 acc[8][4];
  #pragma unroll
  for (int r = 0; r < 8; ++r)
    #pragma unroll
    for (int m = 0; m < 4; ++m) acc[r][m] = (f32x4){0.f, 0.f, 0.f, 0.f};

  // prologue: stage chunk 0 into buf 0, preload step-0 A frags, drain
  #pragma unroll
  for (int r = 0; r < 8; ++r)
    gload_lds16(gbase + (size_t)r * XE_U4, sw + (r << 6));
  bf16x8 A0[4], A1[4];
  #pragma unroll
  for (int mt = 0; mt < 4; ++mt)
    A0[mt] = __builtin_bit_cast(bf16x8, Ahi[(Qbeg + 24 - 8 * mt) * 64 + l]);
  asm volatile("s_waitcnt vmcnt(0)" ::: "memory");

  int buf = 0, Qi = 0;
  for (int p = 0; p < QQ / 2; ++p) {         // 36 pairs = 72 steps
    FIR_STEP(A0, A1);
    FIR_STEP(A1, A0);
  }

  // ---- combine 4 Q-quarter partials in LDS (phased, disjoint mt slices) ----
  __syncthreads();
  float* C = (float*)sbB;                    // 8 rows x 1024 t (32 KB)
  const int co = (q << 2) + (n << 4);        // C/D: col=n, row=(q*4+reg)
  #pragma unroll
  for (int ph = 0; ph < 4; ++ph) {
    const int mt = (w + ph) & 3;
    float* cp = C + (mt << 8) + co;
    if (ph == 0) {
      #pragma unroll
      for (int r = 0; r < 8; ++r)
        *(f32x4*)(cp + (r << 10)) = acc[r][mt];
    } else {
      #pragma unroll
      for (int r = 0; r < 8; ++r) {
        f32x4 v = *(f32x4*)(cp + (r << 10));
        v += acc[r][mt];
        *(f32x4*)(cp + (r << 10)) = v;
      }
    }
    __syncthreads();
  }

  // ---- coalesced store: 2048 f32x4, 256 threads x 8 ----
  #pragma unroll
  for (int u = 0; u < 8; ++u) {
    f32x4 v = ((f32x4*)C)[tid + (u << 8)];
    *(f32x4*)(out + (size_t)(rbase + u) * T_LEN + t0 + (tid << 2)) = v;
  }
}

extern "C" void kernel_launch(void* const* d_in, const int* in_sizes, int n_in,
                              void* d_out, int out_size, void* d_ws, size_t ws_size,
                              hipStream_t stream) {
  const float* x = (const float*)d_in[0];
  const float* k = (const float*)d_in[1];
  float* out = (float*)d_out;
  char* ws = (char*)d_ws;
  if (ws_size < (size_t)WS_END) return;

  float*  kz  = (float*)(ws + WS_KZ);
  float*  g   = (float*)(ws + WS_G);
  __bf16* Ahi = (__bf16*)(ws + WS_AHI);
  __bf16* xe  = (__bf16*)(ws + WS_XE);

  k_build_xe<<<dim3((XE_LEN / 8 + 255) / 256, 32), dim3(256), 0, stream>>>(
      x, xe, k, kz, g);
  k_autocorr<<<dim3(32, 16), dim3(256), 0, stream>>>(k, kz, g);
  k_build_afrag<<<dim3(NCHUNK), dim3(256), 0, stream>>>(g, Ahi);
  k_fir_mfma<<<dim3(512), dim3(256), 0, stream>>>(
      (const uint4*)xe, (const uint4*)Ahi, out);
}